// Round 1
// baseline (141.875 us; speedup 1.0000x reference)
//
#include <hip/hip_runtime.h>
#include <stdint.h>

#define NQ 10
#define DIMQ 1024
#define BATCH 4096

// ------------------------------------------------------- gate coefficients ---
// Gg[g*8+..] = Re/Im of the 2x2 rotation entries a,b,c,d (verified layout from
// the previous pipeline's normalize_rows).
__global__ __launch_bounds__(64) void prep_g(const float* __restrict__ wts,
                                             float* __restrict__ Gg) {
  int g = threadIdx.x;
  if (g < 40) {
    float phi = wts[g * 3 + 0], th = wts[g * 3 + 1], om = wts[g * 3 + 2];
    float ct = cosf(0.5f * th), s = sinf(0.5f * th);
    float ap = 0.5f * (phi + om), am = 0.5f * (phi - om);
    float cp = cosf(ap), spp = sinf(ap), cm = cosf(am), sm = sinf(am);
    Gg[g * 8 + 0] = ct * cp;  Gg[g * 8 + 1] = -ct * spp;  // a = e^{-i(phi+om)/2} c
    Gg[g * 8 + 2] = -s * cm;  Gg[g * 8 + 3] = -s * sm;    // b = -e^{+i(phi-om)/2} s
    Gg[g * 8 + 4] = s * cm;   Gg[g * 8 + 5] = -s * sm;    // c = e^{-i(phi-om)/2} s
    Gg[g * 8 + 6] = ct * cp;  Gg[g * 8 + 7] = ct * spp;   // d = e^{+i(phi+om)/2} c
  }
}

// Composition of the layer's 10 CNOTs as a GF(2)-linear index map (scatter
// form): gate q has control bit c=9-q, target bit t=(c-r) mod 10, applied in
// q order. Linear => perm(a^b) = perm(a)^perm(b); the e<<6 part constant-folds.
__device__ __forceinline__ int cperm(int x, int r) {
  #pragma unroll
  for (int q = 0; q < NQ; ++q) {
    const int c = 9 - q;
    int t = c - r; if (t < 0) t += NQ;
    x ^= ((x >> c) & 1) << t;
  }
  return x;
}

// ------------------------------------------------------- fused simulation ---
// One batch row per wave (4096 waves = 16/CU). State: 16 complex amps/lane,
// idx = (e<<6)|lane. Bits 0-5 = lane bits (shfl_xor), bits 6-9 = reg bits.
// CNOT layers 0-2: single LDS permutation per wave (disjoint 8 KB slices,
// no barriers). CNOT layer 3: folded into the sign evaluation.
__global__ __launch_bounds__(256, 4) void vqc_sim(const float* __restrict__ X,
                                                  const float* __restrict__ Gg,
                                                  const float* __restrict__ W,
                                                  const float* __restrict__ bias,
                                                  float* __restrict__ out) {
  __shared__ float2 lbuf[4][DIMQ];   // 32 KB: per-wave private 1024-amp slice
  const int lane = threadIdx.x & 63;
  const int w = threadIdx.x >> 6;
  const int row = blockIdx.x * 4 + w;

  float sR[16], sI[16];

  // ---- load + normalize (fused) ----
  const float* xr = X + (size_t)row * DIMQ;
  float ss = 0.f;
  #pragma unroll
  for (int e = 0; e < 16; ++e) {
    sR[e] = xr[(e << 6) | lane];     // perfectly coalesced dword loads
    ss += sR[e] * sR[e];
    sI[e] = 0.f;
  }
  #pragma unroll
  for (int off = 32; off > 0; off >>= 1) ss += __shfl_xor(ss, off, 64);
  const float rn = rsqrtf(ss);
  #pragma unroll
  for (int e = 0; e < 16; ++e) sR[e] *= rn;

  // ---- 4 layers: 10 rotations + CNOT permutation ----
  #pragma unroll
  for (int l = 0; l < 4; ++l) {
    #pragma unroll
    for (int q = 0; q < NQ; ++q) {
      const float* G = Gg + (l * NQ + q) * 8;    // uniform -> scalar loads
      const float G0 = G[0], G1 = G[1], G2 = G[2], G3 = G[3];
      const float G4 = G[4], G5 = G[5], G6 = G[6], G7 = G[7];
      const int p = 9 - q;                       // qubit q <-> index bit p
      if (p >= 6) {                              // reg bit: in-register butterfly
        const int mt = 1 << (p - 6);
        #pragma unroll
        for (int e0 = 0; e0 < 16; ++e0) {
          if (e0 & mt) continue;
          const int e1 = e0 | mt;
          float r0 = sR[e0], i0 = sI[e0], r1 = sR[e1], i1 = sI[e1];
          sR[e0] = G0*r0 - G1*i0 + G2*r1 - G3*i1;
          sI[e0] = G0*i0 + G1*r0 + G2*i1 + G3*r1;
          sR[e1] = G4*r0 - G5*i0 + G6*r1 - G7*i1;
          sI[e1] = G4*i0 + G5*r0 + G6*i1 + G7*r1;
        }
      } else {                                   // lane bit: shfl butterfly
        const int m = 1 << p;
        const int L = (lane >> p) & 1;
        const float aR = L ? G6 : G0, aI = L ? G7 : G1;
        const float bR = L ? G4 : G2, bI = L ? G5 : G3;
        #pragma unroll
        for (int e = 0; e < 16; ++e) {
          float oR = __shfl_xor(sR[e], m, 64);
          float oI = __shfl_xor(sI[e], m, 64);
          float rr = sR[e], ii = sI[e];
          sR[e] = aR*rr - aI*ii + bR*oR - bI*oI;
          sI[e] = aR*ii + aI*rr + bR*oI + bI*oR;
        }
      }
    }
    if (l < 3) {                                 // physical permutation, r = l+1
      const int r = l + 1;
      const int yl = cperm(lane, r);
      #pragma unroll
      for (int e = 0; e < 16; ++e) {
        const int y = yl ^ cperm(e << 6, r);     // second term folds to const
        lbuf[w][y] = make_float2(sR[e], sI[e]);
      }
      // same-wave DS ops are in-order: gather sees the scatter, no barrier
      #pragma unroll
      for (int e = 0; e < 16; ++e) {
        float2 t2 = lbuf[w][(e << 6) | lane];
        sR[e] = t2.x; sI[e] = t2.y;
      }
    }
  }

  // ---- probs -> z (layer-3 perm folded into signs) -> out ----
  float z[10];
  #pragma unroll
  for (int q = 0; q < 10; ++q) z[q] = 0.f;
  const int y3l = cperm(lane, 4);                // layer 3: r = 4
  #pragma unroll
  for (int e = 0; e < 16; ++e) {
    const int y = y3l ^ cperm(e << 6, 4);
    const float pr = sR[e]*sR[e] + sI[e]*sI[e];
    #pragma unroll
    for (int q = 0; q < 10; ++q)
      z[q] += ((y >> (9 - q)) & 1) ? -pr : pr;
  }
  #pragma unroll
  for (int q = 0; q < 10; ++q)
    #pragma unroll
    for (int off = 32; off > 0; off >>= 1) z[q] += __shfl_xor(z[q], off, 64);
  if (lane < 16) {
    float acc = bias[lane];
    #pragma unroll
    for (int q = 0; q < 10; ++q) acc += z[q] * W[lane * 10 + q];
    out[(size_t)row * 16 + lane] = acc;
  }
}

extern "C" void kernel_launch(void* const* d_in, const int* in_sizes, int n_in,
                              void* d_out, int out_size, void* d_ws, size_t ws_size,
                              hipStream_t stream) {
  const float* X    = (const float*)d_in[0];
  const float* wts  = (const float*)d_in[1];
  const float* W    = (const float*)d_in[2];
  const float* bias = (const float*)d_in[3];
  float* out = (float*)d_out;
  float* Gg = (float*)d_ws;   // 40 gates x 8 coeffs = 1.25 KB

  hipLaunchKernelGGL(prep_g,  dim3(1),         dim3(64),  0, stream, wts, Gg);
  hipLaunchKernelGGL(vqc_sim, dim3(BATCH / 4), dim3(256), 0, stream, X, Gg, W, bias, out);
}

// Round 2
// 129.705 us; speedup vs baseline: 1.0938x; 1.0938x over previous
//
#include <hip/hip_runtime.h>
#include <stdint.h>

#define NQ 10
#define DIMQ 1024
#define BATCH 4096

// ------------------------------------------------------- gate coefficients ---
// Gg[g*8+..] = Re/Im of the 2x2 rotation entries a,b,c,d.
__global__ __launch_bounds__(64) void prep_g(const float* __restrict__ wts,
                                             float* __restrict__ Gg) {
  int g = threadIdx.x;
  if (g < 40) {
    float phi = wts[g * 3 + 0], th = wts[g * 3 + 1], om = wts[g * 3 + 2];
    float ct = cosf(0.5f * th), s = sinf(0.5f * th);
    float ap = 0.5f * (phi + om), am = 0.5f * (phi - om);
    float cp = cosf(ap), spp = sinf(ap), cm = cosf(am), sm = sinf(am);
    Gg[g * 8 + 0] = ct * cp;  Gg[g * 8 + 1] = -ct * spp;  // a = e^{-i(phi+om)/2} c
    Gg[g * 8 + 2] = -s * cm;  Gg[g * 8 + 3] = -s * sm;    // b = -e^{+i(phi-om)/2} s
    Gg[g * 8 + 4] = s * cm;   Gg[g * 8 + 5] = -s * sm;    // c = e^{-i(phi-om)/2} s
    Gg[g * 8 + 6] = ct * cp;  Gg[g * 8 + 7] = ct * spp;   // d = e^{+i(phi+om)/2} c
  }
}

// Layer's 10 CNOTs composed as a GF(2)-linear index map (scatter form):
// gate q has control bit c=9-q, target t=(c-r) mod 10, applied in q order.
__host__ __device__ constexpr int cperm_c(int x, int r) {
  for (int q = 0; q < NQ; ++q) {
    const int c = 9 - q;
    int t = c - r; if (t < 0) t += NQ;
    x ^= ((x >> c) & 1) << t;
  }
  return x;
}

// One rotation gate on index bit P. P is a TEMPLATE parameter so every state
// array index is compile-time static even if outer loops stay rolled
// (R1 post-mortem: runtime p -> dynamic indexing -> 32 MB scratch traffic).
template<int P>
__device__ __forceinline__ void rot_gate(float (&sR)[16], float (&sI)[16],
                                         const float* __restrict__ G, int lane) {
  const float G0 = G[0], G1 = G[1], G2 = G[2], G3 = G[3];
  const float G4 = G[4], G5 = G[5], G6 = G[6], G7 = G[7];
  if constexpr (P >= 6) {                        // register bit: in-reg butterfly
    constexpr int mt = 1 << (P - 6);
    #pragma unroll
    for (int e0 = 0; e0 < 16; ++e0) {
      if (e0 & mt) continue;
      const int e1 = e0 | mt;
      float r0 = sR[e0], i0 = sI[e0], r1 = sR[e1], i1 = sI[e1];
      sR[e0] = G0*r0 - G1*i0 + G2*r1 - G3*i1;
      sI[e0] = G0*i0 + G1*r0 + G2*i1 + G3*r1;
      sR[e1] = G4*r0 - G5*i0 + G6*r1 - G7*i1;
      sI[e1] = G4*i0 + G5*r0 + G6*i1 + G7*r1;
    }
  } else {                                       // lane bit: shfl butterfly
    constexpr int m = 1 << P;
    const int L = (lane >> P) & 1;
    const float aR = L ? G6 : G0, aI = L ? G7 : G1;
    const float bR = L ? G4 : G2, bI = L ? G5 : G3;
    #pragma unroll
    for (int e = 0; e < 16; ++e) {
      float oR = __shfl_xor(sR[e], m, 64);
      float oI = __shfl_xor(sI[e], m, 64);
      float rr = sR[e], ii = sI[e];
      sR[e] = aR*rr - aI*ii + bR*oR - bI*oI;
      sI[e] = aR*ii + aI*rr + bR*oI + bI*oR;
    }
  }
}

// ------------------------------------------------------- fused simulation ---
// One batch row per wave. idx = (e<<6)|lane: bits 0-5 lane (shfl), 6-9 reg.
// CNOT layers 0-2: one LDS permutation per wave (disjoint slices, no
// barriers; same-wave DS ops are in-order). Layer 3 folded into signs.
__global__ __launch_bounds__(256, 4) void vqc_sim(const float* __restrict__ X,
                                                  const float* __restrict__ Gg,
                                                  const float* __restrict__ W,
                                                  const float* __restrict__ bias,
                                                  float* __restrict__ out) {
  __shared__ float2 lbuf[4][DIMQ];   // 32 KB: per-wave private 1024-amp slice
  const int lane = threadIdx.x & 63;
  const int w = threadIdx.x >> 6;
  const int row = blockIdx.x * 4 + w;

  float sR[16], sI[16];

  // ---- load + normalize (fused) ----
  const float* xr = X + (size_t)row * DIMQ;
  float ss = 0.f;
  #pragma unroll
  for (int e = 0; e < 16; ++e) {
    sR[e] = xr[(e << 6) | lane];     // coalesced dword loads
    ss += sR[e] * sR[e];
    sI[e] = 0.f;
  }
  #pragma unroll
  for (int off = 32; off > 0; off >>= 1) ss += __shfl_xor(ss, off, 64);
  const float rn = rsqrtf(ss);
  #pragma unroll
  for (int e = 0; e < 16; ++e) sR[e] *= rn;

  // ---- 4 layers; layer loop ROLLED (body ~13 KB, fits I-cache) ----
  #pragma unroll 1
  for (int l = 0; l < 4; ++l) {
    const float* Gl = Gg + l * 80;
    rot_gate<9>(sR, sI, Gl + 0,  lane);   // q=0 .. q=9 -> P=9-q
    rot_gate<8>(sR, sI, Gl + 8,  lane);
    rot_gate<7>(sR, sI, Gl + 16, lane);
    rot_gate<6>(sR, sI, Gl + 24, lane);
    rot_gate<5>(sR, sI, Gl + 32, lane);
    rot_gate<4>(sR, sI, Gl + 40, lane);
    rot_gate<3>(sR, sI, Gl + 48, lane);
    rot_gate<2>(sR, sI, Gl + 56, lane);
    rot_gate<1>(sR, sI, Gl + 64, lane);
    rot_gate<0>(sR, sI, Gl + 72, lane);
    if (l < 3) {                           // physical permutation, r = l+1
      const int r = l + 1;
      const int yl = cperm_c(lane, r);               // per-lane VALU
      const int c6 = cperm_c(1 << 6, r);             // wave-uniform (SALU)
      const int c7 = cperm_c(1 << 7, r);
      const int c8 = cperm_c(1 << 8, r);
      const int c9 = cperm_c(1 << 9, r);
      #pragma unroll
      for (int e = 0; e < 16; ++e) {
        const int ye = ((e & 1) ? c6 : 0) ^ ((e & 2) ? c7 : 0) ^
                       ((e & 4) ? c8 : 0) ^ ((e & 8) ? c9 : 0);
        lbuf[w][yl ^ ye] = make_float2(sR[e], sI[e]);
      }
      // same-wave DS ordering guarantees the gather sees the scatter
      #pragma unroll
      for (int e = 0; e < 16; ++e) {
        float2 t2 = lbuf[w][(e << 6) | lane];
        sR[e] = t2.x; sI[e] = t2.y;
      }
    }
  }

  // ---- probs -> z (layer-3 perm folded into signs, r=4 static) ----
  float z[10];
  #pragma unroll
  for (int q = 0; q < 10; ++q) z[q] = 0.f;
  const int y3l = cperm_c(lane, 4);
  #pragma unroll
  for (int e = 0; e < 16; ++e) {
    constexpr int K = 4;                  // silence unused warning paths
    (void)K;
    const int y = y3l ^ cperm_c(e << 6, 4);   // compile-time constant per e
    const float pr = sR[e]*sR[e] + sI[e]*sI[e];
    #pragma unroll
    for (int q = 0; q < 10; ++q)
      z[q] += ((y >> (9 - q)) & 1) ? -pr : pr;
  }
  #pragma unroll
  for (int q = 0; q < 10; ++q)
    #pragma unroll
    for (int off = 32; off > 0; off >>= 1) z[q] += __shfl_xor(z[q], off, 64);
  if (lane < 16) {
    float acc = bias[lane];
    #pragma unroll
    for (int q = 0; q < 10; ++q) acc += z[q] * W[lane * 10 + q];
    out[(size_t)row * 16 + lane] = acc;
  }
}

extern "C" void kernel_launch(void* const* d_in, const int* in_sizes, int n_in,
                              void* d_out, int out_size, void* d_ws, size_t ws_size,
                              hipStream_t stream) {
  const float* X    = (const float*)d_in[0];
  const float* wts  = (const float*)d_in[1];
  const float* W    = (const float*)d_in[2];
  const float* bias = (const float*)d_in[3];
  float* out = (float*)d_out;
  float* Gg = (float*)d_ws;   // 40 gates x 8 coeffs = 1.25 KB

  hipLaunchKernelGGL(prep_g,  dim3(1),         dim3(64),  0, stream, wts, Gg);
  hipLaunchKernelGGL(vqc_sim, dim3(BATCH / 4), dim3(256), 0, stream, X, Gg, W, bias, out);
}